// Round 7
// baseline (239.569 us; speedup 1.0000x reference)
//
#include <hip/hip_runtime.h>
#include <hip/hip_fp16.h>

#define M_TOTAL 512
#define N_TOTAL 11008
#define K_TOTAL 4096
#define BM 256
#define BN 32
#define BK 64
#define NT (K_TOTAL / BK)  // 64
#define NUM_GROUPS (N_TOTAL * K_TOTAL / 32)  // 1409024
#define LDK 72             // fallback kernel's padded stride

typedef short bf16x8 __attribute__((ext_vector_type(8)));
typedef _Float16 f16x8 __attribute__((ext_vector_type(8)));
typedef _Float16 f16x2 __attribute__((ext_vector_type(2)));
typedef float f32x4 __attribute__((ext_vector_type(4)));

// pack two fp32 into two bf16 (round-half-up) -> uint32 (fallback path)
__device__ __forceinline__ unsigned int pack2_bf16(float f0, float f1) {
    unsigned int u0 = __builtin_bit_cast(unsigned int, f0) + 0x8000u;
    unsigned int u1 = __builtin_bit_cast(unsigned int, f1) + 0x8000u;
    return (u0 >> 16) | (u1 & 0xFFFF0000u);
}

// async global->LDS 16B DMA (LDS dest must be wave-uniform base + lane*16)
__device__ __forceinline__ void async_ld16(void* lds, const void* g) {
    __builtin_amdgcn_global_load_lds(
        (const __attribute__((address_space(1))) unsigned int*)g,
        (__attribute__((address_space(3))) unsigned int*)lds, 16, 0, 0);
}

// Per-wave dtype detection for weight_norm: 0=f32, 1=f16, 2=bf16.
__device__ __forceinline__ int detect_mode_wave(const void* __restrict__ wn) {
    const int lane = threadIdx.x & 63;
    const unsigned short* u16 = (const unsigned short*)wn;
    const float* f32p = (const float*)wn;
    const float vb = __builtin_bit_cast(float, (unsigned int)u16[lane] << 16);
    const float vh = __half2float(__builtin_bit_cast(__half, u16[lane]));
    const float vf = f32p[lane];
    const unsigned long long mb = __ballot(vb > 0.005f && vb < 0.12f);
    const unsigned long long mh = __ballot(vh > 0.005f && vh < 0.12f);
    (void)vf;
    return (mb == ~0ull) ? 2 : ((mh == ~0ull) ? 1 : 0);
}

// one-shot x fp32 -> f16
__global__ void __launch_bounds__(256)
convert_x_kernel(const float* __restrict__ x, unsigned short* __restrict__ xh) {
    const int i = (blockIdx.x * 256 + threadIdx.x) * 4;
    const float4 v = *(const float4*)&x[i];
    const unsigned int p0 = __builtin_bit_cast(unsigned int, __builtin_amdgcn_cvt_pkrtz(v.x, v.y));
    const unsigned int p1 = __builtin_bit_cast(unsigned int, __builtin_amdgcn_cvt_pkrtz(v.z, v.w));
    *(uint2*)&xh[i] = make_uint2(p0, p1);
}

// one-shot norm prep: per group pack (s=2n/7, c=-n) as 2 f16 in one u32
__global__ void __launch_bounds__(512)
norm_pack_kernel(const void* __restrict__ wn, unsigned int* __restrict__ np) {
    const int mode = detect_mode_wave(wn);
    const int g = blockIdx.x * 512 + threadIdx.x;
    if (g >= NUM_GROUPS) return;
    float n;
    if (mode == 0)      n = ((const float*)wn)[g];
    else if (mode == 1) n = __half2float(((const __half*)wn)[g]);
    else                n = __builtin_bit_cast(float,
                            (unsigned int)((const unsigned short*)wn)[g] << 16);
    np[g] = __builtin_bit_cast(unsigned int,
                __builtin_amdgcn_cvt_pkrtz(n * (2.0f / 7.0f), -n));
}

// -------- main kernel: 512 thr (8 waves), 256x32 tile, f16, role-split --------
__global__ void __launch_bounds__(512, 4)
l3b_gemm_pipe(const _Float16* __restrict__ xh, const int* __restrict__ wq,
              const unsigned int* __restrict__ np, const float* __restrict__ bias,
              float* __restrict__ out)
{
    // XOR-swizzled, unpadded rows: 64 f16 = 128 B; chunk p of row r holds
    // logical chunk p ^ (r & 7).
    __shared__ _Float16 As[2][BM * 64];  // 32 KB x2
    __shared__ _Float16 Bs[2][BN * 64];  // 4 KB x2  -> 72 KB (2 blocks/CU)

    const int tid  = threadIdx.x;

    // XCD swizzle: XCD x owns n-tiles [43x,43x+43); adjacent dispatches on an
    // XCD are the m-pair of one n-tile -> wq rows fetched once, reused from L2.
    const int bid   = blockIdx.x;       // 0..687
    const int local = bid >> 3;         // 0..85 within XCD
    const int m0    = (local & 1) * BM;
    const int n0    = ((local >> 1) + (bid & 7) * 43) * BN;

    const int wid  = tid >> 6;   // 0..7
    const int lane = tid & 63;
    const int quad = lane >> 4;
    const int lm   = lane & 15;
    const int wm   = wid * 32;   // wave m-offset (8 x 32 = 256)

    // ---- B-decode geometry (waves 0-3): thread t<256 owns one 8-weight unit
    const int bt   = tid;            // valid when tid<256
    const int bn_l = bt >> 3;        // 0..31 n-row
    const int bc   = bt & 7;         // logical k-chunk (8 f16)
    const int bkg  = bc >> 2;        // k-group within BK
    const int bsub = bc & 3;         // 8-wt unit within group
    const int ldsB = (bn_l << 6) + ((bc ^ (bn_l & 7)) << 3);

    // ---- A-DMA geometry (waves 4-7): thread u=tid-256 issues 8 x 16B
    const int au    = tid - 256;     // valid when tid>=256
    const int arow0 = au >> 3;       // + j*32
    const int acol  = ((au & 7) ^ ((au >> 3) & 7)) * 8;  // swizzle on global side
    const int aphys = (au & 7) * 8;

    auto stageA = [&](int it, int buf) {
#pragma unroll
        for (int j = 0; j < 8; ++j) {
            const int row = arow0 + j * 32;
            async_ld16((void*)&As[buf][(row << 6) + aphys],
                       &xh[(size_t)(m0 + row) * K_TOTAL + it * 64 + acol]);
        }
    };

    auto loadB = [&](int it, int& b0, int& b1, int& b2, unsigned int& npk) {
        const int g    = (n0 + bn_l) * (K_TOTAL / 32) + it * 2 + bkg;
        const int base = g * 12 + bsub * 3;
        b0 = wq[base]; b1 = wq[base + 1]; b2 = wq[base + 2];
        npk = np[g];
    };

    const __half2 h1024 = __builtin_bit_cast(__half2, 0x64006400u);
    auto decodeB = [&](int b0, int b1, int b2, unsigned int npk, int buf) {
        // broadcast s (lo16) and c (hi16) to both halves
        const __half2 ss = __builtin_bit_cast(__half2,
            __builtin_amdgcn_perm(npk, npk, 0x01000100u));
        const __half2 cc = __builtin_bit_cast(__half2,
            __builtin_amdgcn_perm(npk, npk, 0x03020302u));
        const unsigned int bits =
            (unsigned)b0 | ((unsigned)b1 << 8) | ((unsigned)b2 << 16);
        unsigned int packs[4];
#pragma unroll
        for (int j = 0; j < 4; ++j) {
            const unsigned int q0 = (bits >> (6 * j)) & 7;
            const unsigned int q1 = (bits >> (6 * j + 3)) & 7;
            // (0x6400|q) as f16 == 1024+q exactly; subtract 1024, then w = q*s + c
            const __half2 h = __builtin_bit_cast(__half2,
                (q0 | (q1 << 16)) | 0x64006400u);
            const __half2 q = __hsub2(h, h1024);
            packs[j] = __builtin_bit_cast(unsigned int, __hfma2(q, ss, cc));
        }
        *(uint4*)&Bs[buf][ldsB] = make_uint4(packs[0], packs[1], packs[2], packs[3]);
    };

    f32x4 acc[2][2];
#pragma unroll
    for (int i = 0; i < 2; ++i)
#pragma unroll
        for (int j = 0; j < 2; ++j) acc[i][j] = (f32x4){0.f, 0.f, 0.f, 0.f};

    auto mfmaTile = [&](const _Float16* Asb, const _Float16* Bsb) {
#pragma unroll
        for (int ks = 0; ks < 2; ++ks) {
            const int cswz = (((ks * 4 + quad) ^ (lm & 7)) << 3);
            f16x8 aF[2], bF[2];
#pragma unroll
            for (int mi = 0; mi < 2; ++mi)
                aF[mi] = *(const f16x8*)&Asb[((wm + mi * 16 + lm) << 6) + cswz];
#pragma unroll
            for (int ni = 0; ni < 2; ++ni)
                bF[ni] = *(const f16x8*)&Bsb[((ni * 16 + lm) << 6) + cswz];
#pragma unroll
            for (int mi = 0; mi < 2; ++mi)
#pragma unroll
                for (int ni = 0; ni < 2; ++ni)
                    acc[mi][ni] = __builtin_amdgcn_mfma_f32_16x16x32_f16(
                        aF[mi], bF[ni], acc[mi][ni], 0, 0, 0);
        }
    };

    // named prefetch registers (no dynamic indexing)
    int ba0, ba1, ba2; unsigned int npa;
    int bb0, bb1, bb2; unsigned int npb;

    // prologue
    if (tid < 256) {
        loadB(0, ba0, ba1, ba2, npa);
        decodeB(ba0, ba1, ba2, npa, 0);
        loadB(1, bb0, bb1, bb2, npb);
    } else {
        stageA(0, 0);
    }
    __syncthreads();

    for (int it = 0; it < NT; it += 2) {
        // sub 0: compute tile it from buf0; build tile it+1 in buf1
        if (tid < 256) {
            if (it + 2 < NT) loadB(it + 2, ba0, ba1, ba2, npa);
            if (it + 1 < NT) decodeB(bb0, bb1, bb2, npb, 1);
        } else {
            if (it + 1 < NT) stageA(it + 1, 1);
        }
        mfmaTile(As[0], Bs[0]);
        __syncthreads();

        // sub 1: compute tile it+1 from buf1; build tile it+2 in buf0
        if (tid < 256) {
            if (it + 3 < NT) loadB(it + 3, bb0, bb1, bb2, npb);
            if (it + 2 < NT) decodeB(ba0, ba1, ba2, npa, 0);
        } else {
            if (it + 2 < NT) stageA(it + 2, 0);
        }
        mfmaTile(As[1], Bs[1]);
        __syncthreads();
    }

    // epilogue: C/D layout col=lane&15, row=quad*4+reg
#pragma unroll
    for (int ni = 0; ni < 2; ++ni) {
        const int o  = n0 + ni * 16 + lm;
        const float bv = bias[o];
#pragma unroll
        for (int mi = 0; mi < 2; ++mi) {
#pragma unroll
            for (int r = 0; r < 4; ++r) {
                const int m = m0 + wm + mi * 16 + quad * 4 + r;
                out[m * N_TOTAL + o] = acc[mi][ni][r] + bv;
            }
        }
    }
}

// ---------------- fallback (r2-style bf16) if ws too small ----------------
__global__ void __launch_bounds__(256)
l3b_gemm_kernel(const float* __restrict__ x, const int* __restrict__ wq,
                const void* __restrict__ wnorm, const float* __restrict__ bias,
                float* __restrict__ out)
{
    __shared__ unsigned short As[128 * LDK];
    __shared__ unsigned short Bs[64 * LDK];

    const int mode = detect_mode_wave(wnorm);
    const int tid  = threadIdx.x;
    const int m0   = blockIdx.y * 128;
    const int n0   = blockIdx.x * 64;
    const int wid  = tid >> 6;
    const int lane = tid & 63;
    const int quad = lane >> 4;
    const int lm   = lane & 15;
    const int wm   = (wid >> 1) * 64;
    const int wn   = (wid & 1) * 32;

    f32x4 acc[4][2];
#pragma unroll
    for (int i = 0; i < 4; ++i)
#pragma unroll
        for (int j = 0; j < 2; ++j) acc[i][j] = (f32x4){0.f, 0.f, 0.f, 0.f};

    const int ar = tid >> 4;
    const int ac = (tid & 15) * 4;
    const int gin      = tid >> 1;
    const int half     = tid & 1;
    const int bn_local = gin >> 1;
    const int bkg      = gin & 1;

    for (int it = 0; it < NT; ++it) {
        const int k0 = it * BK;
        __syncthreads();
#pragma unroll
        for (int p = 0; p < 8; ++p) {
            const int row = p * 16 + ar;
            const float4 v = *(const float4*)&x[(m0 + row) * K_TOTAL + k0 + ac];
            *(uint2*)&As[row * LDK + ac] =
                make_uint2(pack2_bf16(v.x, v.y), pack2_bf16(v.z, v.w));
        }
        {
            const int g    = (n0 + bn_local) * (K_TOTAL / 32) + it * 2 + bkg;
            const int base = g * 12 + half * 6;
            const int2 w0 = *(const int2*)&wq[base];
            const int2 w1 = *(const int2*)&wq[base + 2];
            const int2 w2 = *(const int2*)&wq[base + 4];
            float nrm;
            if (mode == 0)      nrm = ((const float*)wnorm)[g];
            else if (mode == 1) nrm = __half2float(((const __half*)wnorm)[g]);
            else                nrm = __builtin_bit_cast(float,
                                    (unsigned int)((const unsigned short*)wnorm)[g] << 16);
            const float a = nrm * (2.0f / 7.0f);
            const float b = -nrm;
            const unsigned int bits0 =
                (unsigned)w0.x | ((unsigned)w0.y << 8) | ((unsigned)w1.x << 16);
            const unsigned int bits1 =
                (unsigned)w1.y | ((unsigned)w2.x << 8) | ((unsigned)w2.y << 16);
            unsigned int packs[8];
#pragma unroll
            for (int t3 = 0; t3 < 2; ++t3) {
                const unsigned int bits = t3 ? bits1 : bits0;
#pragma unroll
                for (int j = 0; j < 4; ++j) {
                    const float f0 = fmaf((float)((bits >> (6 * j)) & 7), a, b);
                    const float f1 = fmaf((float)((bits >> (6 * j + 3)) & 7), a, b);
                    packs[t3 * 4 + j] = pack2_bf16(f0, f1);
                }
            }
            unsigned int* dst = (unsigned int*)&Bs[bn_local * LDK + bkg * 32 + half * 16];
            *(uint4*)dst       = make_uint4(packs[0], packs[1], packs[2], packs[3]);
            *(uint4*)(dst + 4) = make_uint4(packs[4], packs[5], packs[6], packs[7]);
        }
        __syncthreads();
#pragma unroll
        for (int ks = 0; ks < 2; ++ks) {
            const int kb = ks * 32 + quad * 8;
            bf16x8 aF[4], bF[2];
#pragma unroll
            for (int mi = 0; mi < 4; ++mi)
                aF[mi] = *(const bf16x8*)&As[(wm + mi * 16 + lm) * LDK + kb];
#pragma unroll
            for (int ni = 0; ni < 2; ++ni)
                bF[ni] = *(const bf16x8*)&Bs[(wn + ni * 16 + lm) * LDK + kb];
#pragma unroll
            for (int mi = 0; mi < 4; ++mi)
#pragma unroll
                for (int ni = 0; ni < 2; ++ni)
                    acc[mi][ni] = __builtin_amdgcn_mfma_f32_16x16x32_bf16(
                        aF[mi], bF[ni], acc[mi][ni], 0, 0, 0);
        }
    }
#pragma unroll
    for (int ni = 0; ni < 2; ++ni) {
        const int o  = n0 + wn + ni * 16 + lm;
        const float bv = bias[o];
#pragma unroll
        for (int mi = 0; mi < 4; ++mi)
#pragma unroll
            for (int r = 0; r < 4; ++r) {
                const int m = m0 + wm + mi * 16 + quad * 4 + r;
                out[m * N_TOTAL + o] = acc[mi][ni][r] + bv;
            }
    }
}

extern "C" void kernel_launch(void* const* d_in, const int* in_sizes, int n_in,
                              void* d_out, int out_size, void* d_ws, size_t ws_size,
                              hipStream_t stream) {
    const float* x    = (const float*)d_in[0];
    const int*   wq   = (const int*)d_in[1];
    const void*  wn   = d_in[2];
    const float* bias = (const float*)d_in[3];
    float* out = (float*)d_out;

    const size_t xh_off = 256;
    const size_t xh_sz  = (size_t)M_TOTAL * K_TOTAL * 2;          // 4 MB
    const size_t np_off = xh_off + xh_sz;
    const size_t np_sz  = (size_t)NUM_GROUPS * 4;                 // 5.6 MB
    const size_t need   = np_off + np_sz;

    if (ws_size >= need) {
        unsigned short* xh = (unsigned short*)((char*)d_ws + xh_off);
        unsigned int*   np = (unsigned int*)((char*)d_ws + np_off);
        convert_x_kernel<<<(M_TOTAL * K_TOTAL / 4) / 256, 256, 0, stream>>>(x, xh);
        norm_pack_kernel<<<(NUM_GROUPS + 511) / 512, 512, 0, stream>>>(wn, np);
        l3b_gemm_pipe<<<(M_TOTAL / BM) * (N_TOTAL / BN), 512, 0, stream>>>(
            (const _Float16*)xh, wq, np, bias, out);
    } else {
        dim3 grid(N_TOTAL / 64, M_TOTAL / 128);
        l3b_gemm_kernel<<<grid, 256, 0, stream>>>(x, wq, wn, bias, out);
    }
}

// Round 8
// 202.158 us; speedup vs baseline: 1.1851x; 1.1851x over previous
//
#include <hip/hip_runtime.h>
#include <hip/hip_fp16.h>

#define M_TOTAL 512
#define N_TOTAL 11008
#define K_TOTAL 4096
#define BM 128
#define BN 64
#define BK 64
#define NT (K_TOTAL / BK)  // 64
#define NUM_GROUPS (N_TOTAL * K_TOTAL / 32)  // 1409024
#define LDK 72             // fallback kernel's padded stride

typedef short bf16x8 __attribute__((ext_vector_type(8)));
typedef _Float16 f16x8 __attribute__((ext_vector_type(8)));
typedef float f32x4 __attribute__((ext_vector_type(4)));

// pack two fp32 into two bf16 (round-half-up) -> uint32 (fallback path)
__device__ __forceinline__ unsigned int pack2_bf16(float f0, float f1) {
    unsigned int u0 = __builtin_bit_cast(unsigned int, f0) + 0x8000u;
    unsigned int u1 = __builtin_bit_cast(unsigned int, f1) + 0x8000u;
    return (u0 >> 16) | (u1 & 0xFFFF0000u);
}

// async global->LDS 16B DMA (LDS dest must be wave-uniform base + lane*16)
__device__ __forceinline__ void async_ld16(void* lds, const void* g) {
    __builtin_amdgcn_global_load_lds(
        (const __attribute__((address_space(1))) unsigned int*)g,
        (__attribute__((address_space(3))) unsigned int*)lds, 16, 0, 0);
}

// Per-wave dtype detection for weight_norm: 0=f32, 1=f16, 2=bf16.
__device__ __forceinline__ int detect_mode_wave(const void* __restrict__ wn) {
    const int lane = threadIdx.x & 63;
    const unsigned short* u16 = (const unsigned short*)wn;
    const float* f32p = (const float*)wn;
    const float vb = __builtin_bit_cast(float, (unsigned int)u16[lane] << 16);
    const float vh = __half2float(__builtin_bit_cast(__half, u16[lane]));
    const float vf = f32p[lane];
    const unsigned long long mb = __ballot(vb > 0.005f && vb < 0.12f);
    const unsigned long long mh = __ballot(vh > 0.005f && vh < 0.12f);
    (void)vf;
    return (mb == ~0ull) ? 2 : ((mh == ~0ull) ? 1 : 0);
}

// one-shot x fp32 -> f16
__global__ void __launch_bounds__(256)
convert_x_kernel(const float* __restrict__ x, unsigned short* __restrict__ xh) {
    const int i = (blockIdx.x * 256 + threadIdx.x) * 4;
    const float4 v = *(const float4*)&x[i];
    const unsigned int p0 = __builtin_bit_cast(unsigned int, __builtin_amdgcn_cvt_pkrtz(v.x, v.y));
    const unsigned int p1 = __builtin_bit_cast(unsigned int, __builtin_amdgcn_cvt_pkrtz(v.z, v.w));
    *(uint2*)&xh[i] = make_uint2(p0, p1);
}

// one-shot norm prep: per group pack (s=2n/7 lo16, c=-n hi16) as one u32
__global__ void __launch_bounds__(512)
norm_pack_kernel(const void* __restrict__ wn, unsigned int* __restrict__ np) {
    const int mode = detect_mode_wave(wn);
    const int g = blockIdx.x * 512 + threadIdx.x;
    if (g >= NUM_GROUPS) return;
    float n;
    if (mode == 0)      n = ((const float*)wn)[g];
    else if (mode == 1) n = __half2float(((const __half*)wn)[g]);
    else                n = __builtin_bit_cast(float,
                            (unsigned int)((const unsigned short*)wn)[g] << 16);
    np[g] = __builtin_bit_cast(unsigned int,
                __builtin_amdgcn_cvt_pkrtz(n * (2.0f / 7.0f), -n));
}

// ---- main kernel: R6 structure (128x64, 512 thr, 48KB) + f16 + depth-3 wq prefetch
__global__ void __launch_bounds__(512, 6)
l3b_gemm_pipe(const _Float16* __restrict__ xh, const int* __restrict__ wq,
              const unsigned int* __restrict__ np, const float* __restrict__ bias,
              float* __restrict__ out)
{
    // XOR-swizzled, unpadded rows: 64 f16 = 128 B; physical chunk p of row r
    // holds logical chunk p ^ (r & 7).
    __shared__ _Float16 As[2][BM * 64];  // 16 KB x2
    __shared__ _Float16 Bs[2][BN * 64];  // 8 KB x2  -> 48 KB (3 blocks/CU)

    const int tid  = threadIdx.x;

    // XCD swizzle (R5/R6: FETCH 148->60 MB): XCD x walks contiguous n-tiles,
    // its wq slice stays in its own L2.
    const int bid = blockIdx.x;                 // 0..687
    const int w   = (bid & 7) * 86 + (bid >> 3);
    const int m0  = (w & 3) * BM;
    const int n0  = (w >> 2) * BN;

    const int wid  = tid >> 6;   // 0..7
    const int lane = tid & 63;
    const int quad = lane >> 4;
    const int lm   = lane & 15;
    const int wm   = (wid >> 1) * 32;   // 0,32,64,96
    const int wn_  = (wid & 1) * 32;    // 0,32

    // A-DMA: wave wid stages rows wid*8+(lane>>3) + j*64, j=0..1
    const int arow0 = wid * 8 + (lane >> 3);
    const int acol  = ((lane & 7) ^ ((lane >> 3) & 7)) * 8;  // swizzle on global side
    const int aphys = (lane & 7) * 8;

    // B decode: 1 thread per 8 weights (512 thr = 128 groups x 4 subs)
    const int gl   = tid >> 2;     // group-in-tile 0..127
    const int sub  = tid & 3;      // 8-weight unit within group
    const int bn_l = gl >> 1;      // 0..63
    const int kg   = gl & 1;       // k-group within BK
    const int ldsB = (bn_l << 6) + (((kg * 4 + sub) ^ (bn_l & 7)) << 3);

    auto stageA = [&](int it, int buf) {
#pragma unroll
        for (int j = 0; j < 2; ++j) {
            const int row = arow0 + j * 64;
            async_ld16((void*)&As[buf][(row << 6) + aphys],
                       &xh[(size_t)(m0 + row) * K_TOTAL + it * 64 + acol]);
        }
    };

    auto loadB = [&](int it, int& b0, int& b1, int& b2, unsigned int& npk) {
        const int g    = (n0 + bn_l) * (K_TOTAL / 32) + it * 2 + kg;
        const int base = g * 12 + sub * 3;
        b0 = wq[base]; b1 = wq[base + 1]; b2 = wq[base + 2];
        npk = np[g];
    };

    const __half2 h1024 = __builtin_bit_cast(__half2, 0x64006400u);
    auto decodeB = [&](int b0, int b1, int b2, unsigned int npk, int buf) {
        const __half2 ss = __builtin_bit_cast(__half2,
            __builtin_amdgcn_perm(npk, npk, 0x01000100u));   // broadcast s
        const __half2 cc = __builtin_bit_cast(__half2,
            __builtin_amdgcn_perm(npk, npk, 0x03020302u));   // broadcast c
        const unsigned int bits =
            (unsigned)b0 | ((unsigned)b1 << 8) | ((unsigned)b2 << 16);
        unsigned int packs[4];
#pragma unroll
        for (int j = 0; j < 4; ++j) {
            const unsigned int q0 = (bits >> (6 * j)) & 7;
            const unsigned int q1 = (bits >> (6 * j + 3)) & 7;
            // (0x6400|q) as f16 == 1024+q exactly; w = (h-1024)*s + c
            const __half2 h = __builtin_bit_cast(__half2,
                (q0 | (q1 << 16)) | 0x64006400u);
            const __half2 q = __hsub2(h, h1024);
            packs[j] = __builtin_bit_cast(unsigned int, __hfma2(q, ss, cc));
        }
        *(uint4*)&Bs[buf][ldsB] = make_uint4(packs[0], packs[1], packs[2], packs[3]);
    };

    f32x4 acc[2][2];
#pragma unroll
    for (int i = 0; i < 2; ++i)
#pragma unroll
        for (int j = 0; j < 2; ++j) acc[i][j] = (f32x4){0.f, 0.f, 0.f, 0.f};

    auto mfmaTile = [&](const _Float16* Asb, const _Float16* Bsb) {
#pragma unroll
        for (int ks = 0; ks < 2; ++ks) {
            const int cswz = (((ks * 4 + quad) ^ (lm & 7)) << 3);
            f16x8 aF[2], bF[2];
#pragma unroll
            for (int mi = 0; mi < 2; ++mi)
                aF[mi] = *(const f16x8*)&Asb[((wm + mi * 16 + lm) << 6) + cswz];
#pragma unroll
            for (int ni = 0; ni < 2; ++ni)
                bF[ni] = *(const f16x8*)&Bsb[((wn_ + ni * 16 + lm) << 6) + cswz];
#pragma unroll
            for (int mi = 0; mi < 2; ++mi)
#pragma unroll
                for (int ni = 0; ni < 2; ++ni)
                    acc[mi][ni] = __builtin_amdgcn_mfma_f32_16x16x32_f16(
                        aF[mi], bF[ni], acc[mi][ni], 0, 0, 0);
        }
    };

    // 4 named wq-register sets (depth-3 prefetch, no dynamic indexing)
    int a0, a1, a2; unsigned int an;   // set0: tiles 0,4,8,...
    int b0, b1, b2; unsigned int bn;   // set1
    int c0, c1, c2; unsigned int cn;   // set2
    int d0, d1, d2; unsigned int dn;   // set3

    // prologue: fill sets for tiles 0,1,2; decode tile0; stage A tile0
    loadB(0, a0, a1, a2, an);
    loadB(1, b0, b1, b2, bn);
    loadB(2, c0, c1, c2, cn);
    stageA(0, 0);
    decodeB(a0, a1, a2, an, 0);
    __syncthreads();

    // unroll x4: at sub-iter t: stageA(t+1), loadB(t+3), decodeB(t+1), mfma(t)
    for (int it = 0; it < NT; it += 4) {
        // t = it+0: decode set1 -> buf1, load -> set3
        {
            const int t = it;
            if (t + 1 < NT) stageA(t + 1, 1);
            if (t + 3 < NT) loadB(t + 3, d0, d1, d2, dn);
            if (t + 1 < NT) decodeB(b0, b1, b2, bn, 1);
            mfmaTile(As[0], Bs[0]);
            __syncthreads();
        }
        // t = it+1: decode set2 -> buf0, load -> set0
        {
            const int t = it + 1;
            if (t + 1 < NT) stageA(t + 1, 0);
            if (t + 3 < NT) loadB(t + 3, a0, a1, a2, an);
            if (t + 1 < NT) decodeB(c0, c1, c2, cn, 0);
            mfmaTile(As[1], Bs[1]);
            __syncthreads();
        }
        // t = it+2: decode set3 -> buf1, load -> set1
        {
            const int t = it + 2;
            if (t + 1 < NT) stageA(t + 1, 1);
            if (t + 3 < NT) loadB(t + 3, b0, b1, b2, bn);
            if (t + 1 < NT) decodeB(d0, d1, d2, dn, 1);
            mfmaTile(As[0], Bs[0]);
            __syncthreads();
        }
        // t = it+3: decode set0 -> buf0, load -> set2
        {
            const int t = it + 3;
            if (t + 1 < NT) stageA(t + 1, 0);
            if (t + 3 < NT) loadB(t + 3, c0, c1, c2, cn);
            if (t + 1 < NT) decodeB(a0, a1, a2, an, 0);
            mfmaTile(As[1], Bs[1]);
            __syncthreads();
        }
    }

    // epilogue: C/D layout col=lane&15, row=quad*4+reg
#pragma unroll
    for (int ni = 0; ni < 2; ++ni) {
        const int o  = n0 + wn_ + ni * 16 + lm;
        const float bv = bias[o];
#pragma unroll
        for (int mi = 0; mi < 2; ++mi) {
#pragma unroll
            for (int r = 0; r < 4; ++r) {
                const int m = m0 + wm + mi * 16 + quad * 4 + r;
                out[m * N_TOTAL + o] = acc[mi][ni][r] + bv;
            }
        }
    }
}

// ---------------- fallback (r2-style bf16) if ws too small ----------------
__global__ void __launch_bounds__(256)
l3b_gemm_kernel(const float* __restrict__ x, const int* __restrict__ wq,
                const void* __restrict__ wnorm, const float* __restrict__ bias,
                float* __restrict__ out)
{
    __shared__ unsigned short As[128 * LDK];
    __shared__ unsigned short Bs[64 * LDK];

    const int mode = detect_mode_wave(wnorm);
    const int tid  = threadIdx.x;
    const int m0   = blockIdx.y * 128;
    const int n0   = blockIdx.x * 64;
    const int wid  = tid >> 6;
    const int lane = tid & 63;
    const int quad = lane >> 4;
    const int lm   = lane & 15;
    const int wm   = (wid >> 1) * 64;
    const int wn   = (wid & 1) * 32;

    f32x4 acc[4][2];
#pragma unroll
    for (int i = 0; i < 4; ++i)
#pragma unroll
        for (int j = 0; j < 2; ++j) acc[i][j] = (f32x4){0.f, 0.f, 0.f, 0.f};

    const int ar = tid >> 4;
    const int ac = (tid & 15) * 4;
    const int gin      = tid >> 1;
    const int half     = tid & 1;
    const int bn_local = gin >> 1;
    const int bkg      = gin & 1;

    for (int it = 0; it < NT; ++it) {
        const int k0 = it * BK;
        __syncthreads();
#pragma unroll
        for (int p = 0; p < 8; ++p) {
            const int row = p * 16 + ar;
            const float4 v = *(const float4*)&x[(m0 + row) * K_TOTAL + k0 + ac];
            *(uint2*)&As[row * LDK + ac] =
                make_uint2(pack2_bf16(v.x, v.y), pack2_bf16(v.z, v.w));
        }
        {
            const int g    = (n0 + bn_local) * (K_TOTAL / 32) + it * 2 + bkg;
            const int base = g * 12 + half * 6;
            const int2 w0 = *(const int2*)&wq[base];
            const int2 w1 = *(const int2*)&wq[base + 2];
            const int2 w2 = *(const int2*)&wq[base + 4];
            float nrm;
            if (mode == 0)      nrm = ((const float*)wnorm)[g];
            else if (mode == 1) nrm = __half2float(((const __half*)wnorm)[g]);
            else                nrm = __builtin_bit_cast(float,
                                    (unsigned int)((const unsigned short*)wnorm)[g] << 16);
            const float a = nrm * (2.0f / 7.0f);
            const float b = -nrm;
            const unsigned int bits0 =
                (unsigned)w0.x | ((unsigned)w0.y << 8) | ((unsigned)w1.x << 16);
            const unsigned int bits1 =
                (unsigned)w1.y | ((unsigned)w2.x << 8) | ((unsigned)w2.y << 16);
            unsigned int packs[8];
#pragma unroll
            for (int t3 = 0; t3 < 2; ++t3) {
                const unsigned int bits = t3 ? bits1 : bits0;
#pragma unroll
                for (int j = 0; j < 4; ++j) {
                    const float f0 = fmaf((float)((bits >> (6 * j)) & 7), a, b);
                    const float f1 = fmaf((float)((bits >> (6 * j + 3)) & 7), a, b);
                    packs[t3 * 4 + j] = pack2_bf16(f0, f1);
                }
            }
            unsigned int* dst = (unsigned int*)&Bs[bn_local * LDK + bkg * 32 + half * 16];
            *(uint4*)dst       = make_uint4(packs[0], packs[1], packs[2], packs[3]);
            *(uint4*)(dst + 4) = make_uint4(packs[4], packs[5], packs[6], packs[7]);
        }
        __syncthreads();
#pragma unroll
        for (int ks = 0; ks < 2; ++ks) {
            const int kb = ks * 32 + quad * 8;
            bf16x8 aF[4], bF[2];
#pragma unroll
            for (int mi = 0; mi < 4; ++mi)
                aF[mi] = *(const bf16x8*)&As[(wm + mi * 16 + lm) * LDK + kb];
#pragma unroll
            for (int ni = 0; ni < 2; ++ni)
                bF[ni] = *(const bf16x8*)&Bs[(wn + ni * 16 + lm) * LDK + kb];
#pragma unroll
            for (int mi = 0; mi < 4; ++mi)
#pragma unroll
                for (int ni = 0; ni < 2; ++ni)
                    acc[mi][ni] = __builtin_amdgcn_mfma_f32_16x16x32_bf16(
                        aF[mi], bF[ni], acc[mi][ni], 0, 0, 0);
        }
    }
#pragma unroll
    for (int ni = 0; ni < 2; ++ni) {
        const int o  = n0 + wn + ni * 16 + lm;
        const float bv = bias[o];
#pragma unroll
        for (int mi = 0; mi < 4; ++mi)
#pragma unroll
            for (int r = 0; r < 4; ++r) {
                const int m = m0 + wm + mi * 16 + quad * 4 + r;
                out[m * N_TOTAL + o] = acc[mi][ni][r] + bv;
            }
    }
}

extern "C" void kernel_launch(void* const* d_in, const int* in_sizes, int n_in,
                              void* d_out, int out_size, void* d_ws, size_t ws_size,
                              hipStream_t stream) {
    const float* x    = (const float*)d_in[0];
    const int*   wq   = (const int*)d_in[1];
    const void*  wn   = d_in[2];
    const float* bias = (const float*)d_in[3];
    float* out = (float*)d_out;

    const size_t xh_off = 256;
    const size_t xh_sz  = (size_t)M_TOTAL * K_TOTAL * 2;          // 4 MB
    const size_t np_off = xh_off + xh_sz;
    const size_t np_sz  = (size_t)NUM_GROUPS * 4;                 // 5.6 MB
    const size_t need   = np_off + np_sz;

    if (ws_size >= need) {
        unsigned short* xh = (unsigned short*)((char*)d_ws + xh_off);
        unsigned int*   np = (unsigned int*)((char*)d_ws + np_off);
        convert_x_kernel<<<(M_TOTAL * K_TOTAL / 4) / 256, 256, 0, stream>>>(x, xh);
        norm_pack_kernel<<<(NUM_GROUPS + 511) / 512, 512, 0, stream>>>(wn, np);
        l3b_gemm_pipe<<<(M_TOTAL / BM) * (N_TOTAL / BN), 512, 0, stream>>>(
            (const _Float16*)xh, wq, np, bias, out);
    } else {
        dim3 grid(N_TOTAL / 64, M_TOTAL / 128);
        l3b_gemm_kernel<<<grid, 256, 0, stream>>>(x, wq, wn, bias, out);
    }
}